// Round 3
// baseline (1279.912 us; speedup 1.0000x reference)
//
#include <hip/hip_runtime.h>
#include <hip/hip_bf16.h>

// ---------------------------------------------------------------------------
// TextCNN fused pipeline for MI355X (gfx950)
//   emb->bf16 -> gather -> conv{3,4,5}+maxpool (bf16 MFMA) -> linear+sigmoid
//   -> segment_max
// Shapes: V=50000 D=128 C=128 NCLS=200 N=4096 S=128 NVID=256
// R3: 32x32x16 MFMA, 1 ctile/wave/k (balanced 96 ksteps/wave), immediate-
//     offset LDS addressing, launch_bounds(256,3) => no spills, 3 blocks/CU.
//     (R2 failure: 256+ regs -> 1 wave/SIMD + 451MB spill writeback.)
// ---------------------------------------------------------------------------

using bf16_t   = __bf16;
using bf16x4   = __attribute__((ext_vector_type(4))) __bf16;
using bf16x8   = __attribute__((ext_vector_type(8))) __bf16;
using floatx4  = __attribute__((ext_vector_type(4))) float;
using floatx16 = __attribute__((ext_vector_type(16))) float;

#define N_SENT 4096
#define S_LEN  128
#define D_DIM  128
#define C_DIM  128
#define NCLS   200
#define NVID   256
#define V_SZ   50000

// X tile in LDS: 128 real rows + 4 zero pad rows (shifted reads, k<=5),
// row stride 136 bf16 (272B, rows 16B-aligned).
#define X_ROWS   132
#define X_STRIDE 136

// Packed-B (bf16) per kernel size: 4 ctiles * 8*KS ksteps * 512 = 16384*KS
#define BP3_OFF 0
#define BP4_OFF 49152            // 3*16384
#define BP5_OFF 114688           // 7*16384
#define BPACK_ELEMS 196608       // 12*16384

// ws layout (bytes): [0, 384K) bpack | [1M, +6.3M) feat | [8M, +12.8M) emb16
#define FEAT_OFF  (1u << 20)
#define EMB16_OFF (8u << 20)

// ---------------------------------------------------------------------------
// Kernel 0: emb fp32 -> bf16 table (12.8 MB).
// ---------------------------------------------------------------------------
__global__ void prep_emb(const float* __restrict__ emb, bf16_t* __restrict__ emb16) {
  int i4 = blockIdx.x * 256 + threadIdx.x;
  const floatx4 f = __builtin_nontemporal_load((const floatx4*)emb + i4);
  bf16x4 h;
  h.x = (bf16_t)f.x; h.y = (bf16_t)f.y; h.z = (bf16_t)f.z; h.w = (bf16_t)f.w;
  __builtin_nontemporal_store(h, (bf16x4*)emb16 + i4);
}

// ---------------------------------------------------------------------------
// Kernel 1: pack W{3,4,5} (fp32 [KS][D][C]) into 32x32x16 MFMA B-fragments.
// Per k-section: idx = ((ct*(8*KS) + sg)*64 + l)*8 + j
//   value = W[kk = sg*16 + (l>>5)*8 + j][c = ct*32 + (l&31)]
// GEMM-side: lane l reads 16B at base + sg*1024B + l*16B (fully coalesced).
// ---------------------------------------------------------------------------
__global__ void prep_bpack(const float* __restrict__ W3,
                           const float* __restrict__ W4,
                           const float* __restrict__ W5,
                           bf16_t* __restrict__ bpack) {
  int idx = blockIdx.x * 256 + threadIdx.x;
  if (idx >= BPACK_ELEMS) return;
  int KS; const float* W; int rel;
  if (idx < BP4_OFF)      { KS = 3; W = W3; rel = idx; }
  else if (idx < BP5_OFF) { KS = 4; W = W4; rel = idx - BP4_OFF; }
  else                    { KS = 5; W = W5; rel = idx - BP5_OFF; }
  int szct = 8 * KS * 512;                 // elems per ctile section
  int ct   = rel / szct;
  int r2   = rel - ct * szct;
  int sg   = r2 >> 9;                      // kstep 0..8*KS-1
  int r3   = r2 & 511;
  int l    = r3 >> 3;
  int j    = r3 & 7;
  int kk   = sg * 16 + (l >> 5) * 8 + j;
  int c    = ct * 32 + (l & 31);
  bpack[idx] = (bf16_t)W[kk * C_DIM + c];
}

// ---------------------------------------------------------------------------
// Kernel 2: per-sentence conv GEMM + in-register maxpool.
// Block = 256 thr = 4 waves. Wave w owns ctile w (32 cols) for EACH k:
// ksteps/wave = 8*(3+4+5) = 96*4mt MFMAs -> perfectly balanced.
// A: ds_read_b128, all offsets compile-time immediates off one lane base.
// B: temporal loads (L2-resident bpack), 8-frag cache per 128-K chunk,
//    each frag reused x4 across m-tiles.
// ---------------------------------------------------------------------------
template <int KS>
__device__ __forceinline__ void conv_k32(const bf16_t* __restrict__ Xs_lane,
                                         const bf16_t* __restrict__ bp_lane,
                                         const float* __restrict__ bk,
                                         float* __restrict__ feat,
                                         int lane, int sent, int koff, int ct) {
  floatx16 acc[4];
#pragma unroll
  for (int mt = 0; mt < 4; ++mt)
#pragma unroll
    for (int r = 0; r < 16; ++r) acc[mt][r] = 0.f;

#pragma unroll
  for (int c0 = 0; c0 < KS; ++c0) {          // one window offset = 128-K chunk
    bf16x8 bfr[8];
#pragma unroll
    for (int s = 0; s < 8; ++s)
      bfr[s] = *(const bf16x8*)(bp_lane + (c0 * 8 + s) * 512);
#pragma unroll
    for (int mt = 0; mt < 4; ++mt) {
#pragma unroll
      for (int s = 0; s < 8; ++s) {
        const bf16x8 a =
            *(const bf16x8*)(Xs_lane + (mt * 32 + c0) * X_STRIDE + s * 16);
        acc[mt] = __builtin_amdgcn_mfma_f32_32x32x16_bf16(a, bfr[s], acc[mt], 0, 0, 0);
      }
    }
  }

  // Maxpool over valid t then + bias.
  // C/D (32x32): col = lane&31, row = (reg&3) + 8*(reg>>2) + 4*(lane>>5).
  const int h    = lane >> 5;
  const int tlim = S_LEN - KS + 1;
  float mx = -__builtin_inff();
#pragma unroll
  for (int mt = 0; mt < 4; ++mt)
#pragma unroll
    for (int r = 0; r < 16; ++r) {
      const int t = mt * 32 + (r & 3) + 8 * (r >> 2) + 4 * h;
      mx = (t < tlim) ? fmaxf(mx, acc[mt][r]) : mx;
    }
  mx = fmaxf(mx, __shfl_xor(mx, 32));
  const int c = ct * 32 + (lane & 31);
  if (lane < 32)
    __builtin_nontemporal_store(mx + bk[c], &feat[sent * 384 + koff + c]);
}

__global__ __launch_bounds__(256, 3) void conv_gemm(
    const int* __restrict__ input_x, const bf16_t* __restrict__ emb16,
    const bf16_t* __restrict__ bpack, const float* __restrict__ b3,
    const float* __restrict__ b4, const float* __restrict__ b5,
    float* __restrict__ feat) {
  __shared__ __align__(16) bf16_t Xs[X_ROWS * X_STRIDE];
  const int sent = blockIdx.x;
  const int tid  = threadIdx.x;

  // Stage X: 128 bf16 rows, 16 lanes x 16B per row, non-temporal (protect L2).
  {
    const int rip = tid >> 4;
    const int l16 = tid & 15;
#pragma unroll
    for (int r0 = 0; r0 < S_LEN; r0 += 16) {
      const int row   = r0 + rip;
      const int token = __builtin_nontemporal_load(&input_x[sent * S_LEN + row]);
      const bf16x8 v  =
          __builtin_nontemporal_load((const bf16x8*)(emb16 + token * D_DIM + l16 * 8));
      *(bf16x8*)(&Xs[row * X_STRIDE + l16 * 8]) = v;
    }
    for (int i = tid; i < 4 * X_STRIDE; i += 256)
      Xs[128 * X_STRIDE + i] = (bf16_t)0.f;
  }
  __syncthreads();

  const int wv   = tid >> 6;                 // wave id = ctile
  const int lane = tid & 63;
  const bf16_t* Xs_lane = Xs + (lane & 31) * X_STRIDE + (lane >> 5) * 8;
  const int lane16 = lane * 8;               // B lane offset (elems)

  conv_k32<3>(Xs_lane, bpack + BP3_OFF + wv * (8 * 3 * 512) + lane16, b3, feat,
              lane, sent, 0, wv);
  conv_k32<4>(Xs_lane, bpack + BP4_OFF + wv * (8 * 4 * 512) + lane16, b4, feat,
              lane, sent, 128, wv);
  conv_k32<5>(Xs_lane, bpack + BP5_OFF + wv * (8 * 5 * 512) + lane16, b5, feat,
              lane, sent, 256, wv);
}

// ---------------------------------------------------------------------------
// Kernel 3: logits = feat @ Wout + bout; sigmoid; max over 16 sentences/video.
// ---------------------------------------------------------------------------
__global__ void classify(const float* __restrict__ feat,
                         const float* __restrict__ Wout,
                         const float* __restrict__ bout,
                         float* __restrict__ out) {
  __shared__ float fs[16 * 384];
  const int vid = blockIdx.x;
  const int tid = threadIdx.x;
  for (int i = tid; i < 16 * 384; i += 256) fs[i] = feat[vid * 16 * 384 + i];
  __syncthreads();
  if (tid < NCLS) {
    float acc[16];
#pragma unroll
    for (int s = 0; s < 16; ++s) acc[s] = 0.f;
    for (int d = 0; d < 384; ++d) {
      const float wv = Wout[d * NCLS + tid];
#pragma unroll
      for (int s = 0; s < 16; ++s) acc[s] = fmaf(fs[s * 384 + d], wv, acc[s]);
    }
    const float b = bout[tid];
    float vmax = -__builtin_inff();
#pragma unroll
    for (int s = 0; s < 16; ++s) {
      const float sc = 1.f / (1.f + __expf(-(acc[s] + b)));
      vmax = fmaxf(vmax, sc);
    }
    out[vid * NCLS + tid] = vmax;
  }
}

// ---------------------------------------------------------------------------
extern "C" void kernel_launch(void* const* d_in, const int* in_sizes, int n_in,
                              void* d_out, int out_size, void* d_ws, size_t ws_size,
                              hipStream_t stream) {
  const int*   input_x = (const int*)d_in[0];
  // d_in[1] = segment_ids: fixed i//16 grouping, folded into classify()
  const float* emb  = (const float*)d_in[2];
  const float* W3   = (const float*)d_in[3];
  const float* b3   = (const float*)d_in[4];
  const float* W4   = (const float*)d_in[5];
  const float* b4   = (const float*)d_in[6];
  const float* W5   = (const float*)d_in[7];
  const float* b5   = (const float*)d_in[8];
  const float* Wout = (const float*)d_in[9];
  const float* bout = (const float*)d_in[10];

  bf16_t* bpack = (bf16_t*)d_ws;
  float*  feat  = (float*)((char*)d_ws + FEAT_OFF);
  bf16_t* emb16 = (bf16_t*)((char*)d_ws + EMB16_OFF);
  float*  out   = (float*)d_out;

  prep_emb<<<(V_SZ * D_DIM) / 4 / 256, 256, 0, stream>>>(emb, emb16);
  prep_bpack<<<BPACK_ELEMS / 256, 256, 0, stream>>>(W3, W4, W5, bpack);
  conv_gemm<<<N_SENT, 256, 0, stream>>>(input_x, emb16, bpack, b3, b4, b5, feat);
  classify<<<NVID, 256, 0, stream>>>(feat, Wout, bout, out);
}

// Round 4
// 289.688 us; speedup vs baseline: 4.4182x; 4.4182x over previous
//
#include <hip/hip_runtime.h>
#include <hip/hip_bf16.h>

// ---------------------------------------------------------------------------
// TextCNN fused pipeline for MI355X (gfx950)
//   emb->bf16 -> gather -> conv{3,4,5}+maxpool (bf16 MFMA) -> linear+sigmoid
//   -> segment_max
// Shapes: V=50000 D=128 C=128 NCLS=200 N=4096 S=128 NVID=256
// R4: R2 tiling (16x16x32, ctile-pairs) but K-chunk loop is a RUNTIME loop
//     (#pragma unroll 1) + sched_barrier between k-sections. R1-R3 all
//     spilled ~0.4-1.7KB/thread (WRITE 0.45-1.9GB) because full unrolling
//     let the scheduler hoist loads across the whole body.
// ---------------------------------------------------------------------------

using bf16_t  = __bf16;
using bf16x4  = __attribute__((ext_vector_type(4))) __bf16;
using bf16x8  = __attribute__((ext_vector_type(8))) __bf16;
using floatx4 = __attribute__((ext_vector_type(4))) float;

#define N_SENT 4096
#define S_LEN  128
#define D_DIM  128
#define C_DIM  128
#define NCLS   200
#define NVID   256
#define V_SZ   50000

// X tile in LDS: 128 real rows + 4 zero pad rows (shifted reads, k<=5),
// row stride 136 bf16 (272B, rows 16B-aligned).
#define X_ROWS   132
#define X_STRIDE 136

// Packed-B (bf16) per kernel size: K*C = k*128*128 elems (16x16 frag layout)
#define BP3_OFF 0
#define BP4_OFF 49152            // 3*16384
#define BP5_OFF 114688           // 7*16384
#define BPACK_ELEMS 196608       // 12*16384

// ws layout (bytes): [0, 384K) bpack | [1M, +6.3M) feat | [8M, +12.8M) emb16
#define FEAT_OFF  (1u << 20)
#define EMB16_OFF (8u << 20)

// ---------------------------------------------------------------------------
// Kernel 0: emb fp32 -> bf16 table (12.8 MB).
// ---------------------------------------------------------------------------
__global__ void prep_emb(const float* __restrict__ emb, bf16_t* __restrict__ emb16) {
  int i4 = blockIdx.x * 256 + threadIdx.x;
  const floatx4 f = __builtin_nontemporal_load((const floatx4*)emb + i4);
  bf16x4 h;
  h.x = (bf16_t)f.x; h.y = (bf16_t)f.y; h.z = (bf16_t)f.z; h.w = (bf16_t)f.w;
  __builtin_nontemporal_store(h, (bf16x4*)emb16 + i4);
}

// ---------------------------------------------------------------------------
// Kernel 1: pack W{3,4,5} (fp32 [KS][D][C]) into bf16 16x16x32 B-fragments.
// Per k: idx = ((ctile*(16*KS) + g)*16 + n)*8 + j ; value = W[g*8+j][ctile*16+n]
// GEMM lane (n=lane&15, q=lane>>4, kstep s): g = s*4+q -> 16B/lane coalesced.
// ---------------------------------------------------------------------------
__global__ void prep_bpack(const float* __restrict__ W3,
                           const float* __restrict__ W4,
                           const float* __restrict__ W5,
                           bf16_t* __restrict__ bpack) {
  int idx = blockIdx.x * 256 + threadIdx.x;
  if (idx >= BPACK_ELEMS) return;
  int KS; const float* W; int rel;
  if (idx < BP4_OFF)      { KS = 3; W = W3; rel = idx; }
  else if (idx < BP5_OFF) { KS = 4; W = W4; rel = idx - BP4_OFF; }
  else                    { KS = 5; W = W5; rel = idx - BP5_OFF; }
  int szct  = 2048 * KS;
  int ctile = rel / szct;
  int r2    = rel - ctile * szct;
  int g     = r2 >> 7;
  int r3    = r2 & 127;
  int n     = r3 >> 3;
  int j     = r3 & 7;
  bpack[idx] = (bf16_t)W[(g * 8 + j) * C_DIM + (ctile * 16 + n)];
}

// ---------------------------------------------------------------------------
// Kernel 2: per-sentence conv GEMM + in-register maxpool.
// Block = 256 thr = 4 waves. Wave w: ctile pair {2w,2w+1} for each k
// -> (3+4+5)*2 chunk-steps/wave, perfectly balanced.
// c0-loop is a RUNTIME loop: live set per iter = acc(64) + bfr(32) + few A.
// B loads temporal (bpack L2-resident); X gather / feat stores non-temporal.
// ---------------------------------------------------------------------------
template <int KS>
__device__ __forceinline__ void conv_k(const bf16_t* Xs_lane,
                                       const bf16_t* bp0, const bf16_t* bp1,
                                       const float* __restrict__ bk,
                                       float* __restrict__ feat,
                                       int m, int q, int lane, int sent,
                                       int koff, int ct0) {
  floatx4 acc[2][8];
#pragma unroll
  for (int ct = 0; ct < 2; ++ct)
#pragma unroll
    for (int mt = 0; mt < 8; ++mt)
      acc[ct][mt] = (floatx4){0.f, 0.f, 0.f, 0.f};

  const bf16_t* Arow = Xs_lane;

#pragma unroll 1
  for (int c0 = 0; c0 < KS; ++c0) {          // one 128-deep K chunk
    bf16x8 bfr0[4], bfr1[4];
#pragma unroll
    for (int st = 0; st < 4; ++st) {
      bfr0[st] = *(const bf16x8*)(bp0 + st * 512);   // temporal: stays in L2
      bfr1[st] = *(const bf16x8*)(bp1 + st * 512);
    }
    bp0 += 2048;
    bp1 += 2048;
#pragma unroll
    for (int mt = 0; mt < 8; ++mt) {
#pragma unroll
      for (int st = 0; st < 4; ++st) {
        const bf16x8 a = *(const bf16x8*)(Arow + mt * 16 * X_STRIDE + st * 32);
        acc[0][mt] = __builtin_amdgcn_mfma_f32_16x16x32_bf16(a, bfr0[st], acc[0][mt], 0, 0, 0);
        acc[1][mt] = __builtin_amdgcn_mfma_f32_16x16x32_bf16(a, bfr1[st], acc[1][mt], 0, 0, 0);
      }
    }
    Arow += X_STRIDE;                        // window shift
  }

  // Maxpool over valid t then + bias. C/D: col=lane&15, row t = mt*16+q*4+r.
  const int tlim = S_LEN - KS + 1;
#pragma unroll
  for (int ct = 0; ct < 2; ++ct) {
    float mx = -__builtin_inff();
#pragma unroll
    for (int mt = 0; mt < 8; ++mt)
#pragma unroll
      for (int r = 0; r < 4; ++r) {
        const int t = mt * 16 + q * 4 + r;
        if (t < tlim) mx = fmaxf(mx, acc[ct][mt][r]);
      }
    mx = fmaxf(mx, __shfl_xor(mx, 16));
    mx = fmaxf(mx, __shfl_xor(mx, 32));
    const int c = (ct0 + ct) * 16 + m;
    if (lane < 16)
      __builtin_nontemporal_store(mx + bk[c], &feat[sent * 384 + koff + c]);
  }
}

__global__ __launch_bounds__(256, 3) void conv_gemm(
    const int* __restrict__ input_x, const bf16_t* __restrict__ emb16,
    const bf16_t* __restrict__ bpack, const float* __restrict__ b3,
    const float* __restrict__ b4, const float* __restrict__ b5,
    float* __restrict__ feat) {
  __shared__ __align__(16) bf16_t Xs[X_ROWS * X_STRIDE];
  const int sent = blockIdx.x;
  const int tid  = threadIdx.x;

  // Stage X: 128 bf16 rows, 16 lanes x 16B per row, non-temporal (protect L2).
  {
    const int rip = tid >> 4;
    const int l16 = tid & 15;
#pragma unroll
    for (int r0 = 0; r0 < S_LEN; r0 += 16) {
      const int row   = r0 + rip;
      const int token = __builtin_nontemporal_load(&input_x[sent * S_LEN + row]);
      const bf16x8 v  =
          __builtin_nontemporal_load((const bf16x8*)(emb16 + token * D_DIM + l16 * 8));
      *(bf16x8*)(&Xs[row * X_STRIDE + l16 * 8]) = v;
    }
    for (int i = tid; i < 4 * X_STRIDE; i += 256)
      Xs[128 * X_STRIDE + i] = (bf16_t)0.f;
  }
  __syncthreads();

  const int wv   = tid >> 6;
  const int lane = tid & 63;
  const int m    = lane & 15;
  const int q    = lane >> 4;
  const bf16_t* Xs_lane = Xs + m * X_STRIDE + q * 8;
  const int     ct0     = 2 * wv;
  const int     blaneoff = q * 128 + m * 8;

  conv_k<3>(Xs_lane, bpack + BP3_OFF + (ct0 + 0) * (2048 * 3) + blaneoff,
            bpack + BP3_OFF + (ct0 + 1) * (2048 * 3) + blaneoff,
            b3, feat, m, q, lane, sent, 0, ct0);
  __builtin_amdgcn_sched_barrier(0);
  conv_k<4>(Xs_lane, bpack + BP4_OFF + (ct0 + 0) * (2048 * 4) + blaneoff,
            bpack + BP4_OFF + (ct0 + 1) * (2048 * 4) + blaneoff,
            b4, feat, m, q, lane, sent, 128, ct0);
  __builtin_amdgcn_sched_barrier(0);
  conv_k<5>(Xs_lane, bpack + BP5_OFF + (ct0 + 0) * (2048 * 5) + blaneoff,
            bpack + BP5_OFF + (ct0 + 1) * (2048 * 5) + blaneoff,
            b5, feat, m, q, lane, sent, 256, ct0);
}

// ---------------------------------------------------------------------------
// Kernel 3: logits = feat @ Wout + bout; sigmoid; max over 16 sentences/video.
// ---------------------------------------------------------------------------
__global__ void classify(const float* __restrict__ feat,
                         const float* __restrict__ Wout,
                         const float* __restrict__ bout,
                         float* __restrict__ out) {
  __shared__ float fs[16 * 384];
  const int vid = blockIdx.x;
  const int tid = threadIdx.x;
  for (int i = tid; i < 16 * 384; i += 256) fs[i] = feat[vid * 16 * 384 + i];
  __syncthreads();
  if (tid < NCLS) {
    float acc[16];
#pragma unroll
    for (int s = 0; s < 16; ++s) acc[s] = 0.f;
    for (int d = 0; d < 384; ++d) {
      const float wv = Wout[d * NCLS + tid];
#pragma unroll
      for (int s = 0; s < 16; ++s) acc[s] = fmaf(fs[s * 384 + d], wv, acc[s]);
    }
    const float b = bout[tid];
    float vmax = -__builtin_inff();
#pragma unroll
    for (int s = 0; s < 16; ++s) {
      const float sc = 1.f / (1.f + __expf(-(acc[s] + b)));
      vmax = fmaxf(vmax, sc);
    }
    out[vid * NCLS + tid] = vmax;
  }
}

// ---------------------------------------------------------------------------
extern "C" void kernel_launch(void* const* d_in, const int* in_sizes, int n_in,
                              void* d_out, int out_size, void* d_ws, size_t ws_size,
                              hipStream_t stream) {
  const int*   input_x = (const int*)d_in[0];
  // d_in[1] = segment_ids: fixed i//16 grouping, folded into classify()
  const float* emb  = (const float*)d_in[2];
  const float* W3   = (const float*)d_in[3];
  const float* b3   = (const float*)d_in[4];
  const float* W4   = (const float*)d_in[5];
  const float* b4   = (const float*)d_in[6];
  const float* W5   = (const float*)d_in[7];
  const float* b5   = (const float*)d_in[8];
  const float* Wout = (const float*)d_in[9];
  const float* bout = (const float*)d_in[10];

  bf16_t* bpack = (bf16_t*)d_ws;
  float*  feat  = (float*)((char*)d_ws + FEAT_OFF);
  bf16_t* emb16 = (bf16_t*)((char*)d_ws + EMB16_OFF);
  float*  out   = (float*)d_out;

  prep_emb<<<(V_SZ * D_DIM) / 4 / 256, 256, 0, stream>>>(emb, emb16);
  prep_bpack<<<BPACK_ELEMS / 256, 256, 0, stream>>>(W3, W4, W5, bpack);
  conv_gemm<<<N_SENT, 256, 0, stream>>>(input_x, emb16, bpack, b3, b4, b5, feat);
  classify<<<NVID, 256, 0, stream>>>(feat, Wout, bout, out);
}